// Round 4
// baseline (163.903 us; speedup 1.0000x reference)
//
#include <hip/hip_runtime.h>

// HetGNN fused kernel, round 18: dual-chain ILP at 512 threads.
// R15-R17: 1024-thr blocks are pinned at 64 VGPR by the allocator regardless
// of amdgpu_waves_per_eu/amdgpu_num_vgpr/__launch_bounds__ (3 independent
// levers, zero effect) -> ~20 regs spill -> 33 MB scratch writes. 512-thr
// blocks empirically get a sane budget (R14: 112 VGPR, no spill).
// This round trades TLP for ILP: back to 512-thr / 8-wave / 1 block/CU
// (2 waves/SIMD), but each wave runs TWO independent graph-pair chains (X,Y)
// interleaved per stage:
//   - every weight fragment is ds_read ONCE and feeds both chains' MFMAs
//     (weight LDS traffic halved);
//   - each chain's scatter->gather RAW latency hides under the other
//     chain's VALU/MFMA (the actual R14 bottleneck).
// Also kills a long-standing scratch source: the dynamically-indexed
// `const float* mats[9]` staging array (rule: runtime-indexed arrays ->
// scratch; ~9-19 MB of WRITE_SIZE across rounds) -> branchless selects.
// Distribution: 256 blk x 8 waves x 2 chains x 2 pi = 8192 pairs exact.
// LDS: sW 96 KB + sAct 8x6 KB + sConst 4.25 KB = 148.25 KB (1 block/CU).

typedef unsigned short u16;
typedef unsigned int   u32;
typedef __attribute__((ext_vector_type(8))) short short8_t;
typedef __attribute__((ext_vector_type(2))) short short2v;
typedef __attribute__((ext_vector_type(4))) float floatx4;

// u16 offsets of each matrix's fragment block inside sW (fi*512 ordering).
// 96 frags: w51(16) w61(16) w71(16) w52(8) w53(8) w62(8) w63(8) w72(8) w73(8).
#define OFF_W51 0
#define OFF_W61 8192
#define OFF_W71 16384
#define OFF_W52 24576
#define OFF_W53 28672
#define OFF_W62 32768
#define OFF_W63 36864
#define OFF_W72 40960
#define OFF_W73 45056
#define WS_U16  49152

// f32 offsets inside the sConst LDS table.
#define CB51 0
#define CB52 64
#define CB53 128
#define CB61 192
#define CB62 256
#define CB63 320
#define CB71 384
#define CB72 448
#define CB73 512
#define CWPO 576
#define CBPO 704
#define CWPA 768
#define CBPA 832
#define CWPE 896
#define CBPE 1024
#define CSZ  1088

#define PW_U16 3072   // per-wave LDS: 2 chains x (BUF 1024 | aPb 512)

struct Params {
  const float *ap, *ef;
  const float *wpa, *bpa, *wpe, *bpe;
  const float *w51, *b51, *w52, *b52, *w53, *b53;
  const float *w61, *b61, *w62, *b62, *w63, *b63;
  const float *w71, *b71, *w72, *b72, *w73, *b73;
  const float *wpost, *bpost;
  float *out;
  int gtot;
};

// Pack two f32 to bf16 pair: round-half-up via +0x8000, then one byte-perm.
__device__ __forceinline__ u32 pk2(float a, float b) {
  const u32 ua = __float_as_uint(a) + 0x8000u;
  const u32 ub = __float_as_uint(b) + 0x8000u;
  return __builtin_amdgcn_perm(ub, ua, 0x07060302u);  // {ub[31:16], ua[31:16]}
}
__device__ __forceinline__ float blo(u32 v) { return __uint_as_float(v << 16); }
__device__ __forceinline__ float bhi(u32 v) { return __uint_as_float(v & 0xffff0000u); }
// packed int16 max: exact bf16-max in our use because the final max-with-0
// (deferred relu) dominates any mis-ordered negative intermediate.
__device__ __forceinline__ u32 pkmax(u32 a, u32 b) {
  const short2v r = __builtin_elementwise_max(__builtin_bit_cast(short2v, a),
                                              __builtin_bit_cast(short2v, b));
  return __builtin_bit_cast(u32, r);
}
__device__ __forceinline__ u32 ror16(u32 x) { return (x >> 16) | (x << 16); }
__device__ __forceinline__ float sel4(int i, float x0, float x1, float x2, float x3) {
  const float lo = (i & 1) ? x1 : x0;
  const float hi = (i & 1) ? x3 : x2;
  return (i & 2) ? hi : lo;
}

__device__ __forceinline__ floatx4 mfma16(short8_t a, short8_t b, floatx4 c) {
  return __builtin_amdgcn_mfma_f32_16x16x32_bf16(a, b, c, 0, 0, 0);
}
__device__ __forceinline__ short8_t ldA(const u16* buf, int l) {
  return *(const short8_t*)(buf + l * 8);
}

// Dual-chain K=64 layer: each B fragment is loaded ONCE and feeds both
// chains; X/Y MFMAs alternate so the two acc dependency chains interleave.
template<int TSTRIDE>
__device__ __forceinline__ void layerK64R2(floatx4* aX, floatx4* aY,
                                           short8_t x0, short8_t x1,
                                           short8_t y0, short8_t y1,
                                           const u16* B, int l) {
#pragma unroll
  for (int t = 0; t < 4; ++t) {
    const short8_t b0 = *(const short8_t*)(B + (t * TSTRIDE + 0) * 512 + l * 8);
    const short8_t b1 = *(const short8_t*)(B + (t * TSTRIDE + 1) * 512 + l * 8);
    aX[t] = mfma16(x0, b0, aX[t]);
    aY[t] = mfma16(y0, b0, aY[t]);
    aX[t] = mfma16(x1, b1, aX[t]);
    aY[t] = mfma16(y1, b1, aY[t]);
  }
}

// Dual-chain K=128 layer (4 A-frags per chain), shared B loads.
__device__ __forceinline__ void layerK128R2(floatx4* aX, floatx4* aY,
                                            const short8_t* fx, const short8_t* fy,
                                            const u16* B, int l) {
#pragma unroll
  for (int t = 0; t < 4; ++t)
#pragma unroll
    for (int h = 0; h < 4; ++h) {
      const short8_t b = *(const short8_t*)(B + (t * 4 + h) * 512 + l * 8);
      aX[t] = mfma16(fx[h], b, aX[t]);
      aY[t] = mfma16(fy[h], b, aY[t]);
    }
}

// C-layout regs -> A-frag-swizzled bf16 LDS (with relu). Element (m=4q+r, f=16t+n).
__device__ __forceinline__ void scatter_relu_bf16(u16* dst, const floatx4* acc, int q, int n) {
#pragma unroll
  for (int t = 0; t < 4; ++t) {
    const int kk = (t & 1) * 2 + (n >> 3);
    u16* base = dst + (t >> 1) * 512 + (n & 7);
    const u32 v01 = pk2(fmaxf(acc[t][0], 0.f), fmaxf(acc[t][1], 0.f));
    const u32 v23 = pk2(fmaxf(acc[t][2], 0.f), fmaxf(acc[t][3], 0.f));
    base[(4 * q + 0 + 16 * kk) * 8] = (u16)v01;
    base[(4 * q + 1 + 16 * kk) * 8] = (u16)(v01 >> 16);
    base[(4 * q + 2 + 16 * kk) * 8] = (u16)v23;
    base[(4 * q + 3 + 16 * kk) * 8] = (u16)(v23 >> 16);
  }
}

// Same, no relu (eP can be negative).
__device__ __forceinline__ void scatter_bf16(u16* dst, const floatx4* acc, int q, int n) {
#pragma unroll
  for (int t = 0; t < 4; ++t) {
    const int kk = (t & 1) * 2 + (n >> 3);
    u16* base = dst + (t >> 1) * 512 + (n & 7);
    const u32 v01 = pk2(acc[t][0], acc[t][1]);
    const u32 v23 = pk2(acc[t][2], acc[t][3]);
    base[(4 * q + 0 + 16 * kk) * 8] = (u16)v01;
    base[(4 * q + 1 + 16 * kk) * 8] = (u16)(v01 >> 16);
    base[(4 * q + 2 + 16 * kk) * 8] = (u16)v23;
    base[(4 * q + 3 + 16 * kk) * 8] = (u16)(v23 >> 16);
  }
}

// Packed src: src[2t+half] holds rows (4q+2half, 4q+2half+1).
__device__ __forceinline__ void scatter_pk(u16* dst, const u32* src, int q, int n) {
#pragma unroll
  for (int t = 0; t < 4; ++t) {
    const int kk = (t & 1) * 2 + (n >> 3);
    u16* base = dst + (t >> 1) * 512 + (n & 7);
#pragma unroll
    for (int half = 0; half < 2; ++half) {
      const u32 v = src[2 * t + half];
      base[(4 * q + 2 * half + 0 + 16 * kk) * 8] = (u16)v;
      base[(4 * q + 2 * half + 1 + 16 * kk) * 8] = (u16)(v >> 16);
    }
  }
}

// aP dedup scatter (8 rows) WITH b61 pre-fold: stores aP + b61 (bf16-rounded).
__device__ __forceinline__ void scatter_aP(u16* dst, const floatx4* acc, int q, int n,
                                           const float* cb61) {
#pragma unroll
  for (int t = 0; t < 4; ++t) {
    const int kk = (t & 1) * 2 + (n >> 3);
    u16* base = dst + (t >> 1) * 256 + (n & 7);
    const float bv = cb61[16 * t + n];
    const u32 v = pk2(acc[t][0] + bv, acc[t][2] + bv);   // rows d=2q,2q+1
    base[(2 * q + 0 + 8 * kk) * 8] = (u16)v;
    base[(2 * q + 1 + 8 * kk) * 8] = (u16)(v >> 16);
  }
}

__device__ __forceinline__ void init_accL(floatx4* acc, const float* cb, int n) {
#pragma unroll
  for (int t = 0; t < 4; ++t) {
    const float b = cb[16 * t + n];
    floatx4 v; v[0] = b; v[1] = b; v[2] = b; v[3] = b;
    acc[t] = v;
  }
}
__device__ __forceinline__ void init_acc0(floatx4* acc) {
#pragma unroll
  for (int t = 0; t < 4; ++t) { acc[t][0] = 0.f; acc[t][1] = 0.f; acc[t][2] = 0.f; acc[t][3] = 0.f; }
}

struct frag2 { short8_t f0, f1; };

__device__ __forceinline__ frag2 make_a(float apv, int q, const float* sc) {
  frag2 r;
#pragma unroll
  for (int h = 0; h < 2; ++h) {
    const int fb = 32 * h + 8 * q;
    const float4 wa0 = *(const float4*)(sc + CWPA + fb);
    const float4 wa1 = *(const float4*)(sc + CWPA + fb + 4);
    const float4 ba0 = *(const float4*)(sc + CBPA + fb);
    const float4 ba1 = *(const float4*)(sc + CBPA + fb + 4);
    uint4 pa;
    pa.x = pk2(fmaxf(fmaf(apv, wa0.x, ba0.x), 0.f), fmaxf(fmaf(apv, wa0.y, ba0.y), 0.f));
    pa.y = pk2(fmaxf(fmaf(apv, wa0.z, ba0.z), 0.f), fmaxf(fmaf(apv, wa0.w, ba0.w), 0.f));
    pa.z = pk2(fmaxf(fmaf(apv, wa1.x, ba1.x), 0.f), fmaxf(fmaf(apv, wa1.y, ba1.y), 0.f));
    pa.w = pk2(fmaxf(fmaf(apv, wa1.z, ba1.z), 0.f), fmaxf(fmaf(apv, wa1.w, ba1.w), 0.f));
    if (h == 0) r.f0 = __builtin_bit_cast(short8_t, pa);
    else        r.f1 = __builtin_bit_cast(short8_t, pa);
  }
  return r;
}

// Pre-layer for one chain: a-frag + e-frags straight into registers.
__device__ __forceinline__ void prelayer(frag2& A, short8_t& e0, short8_t& e1,
                                         const Params& p, const float* sc,
                                         int g0, int q, int n) {
  const float apv = p.ap[(g0 + (n >> 3)) * 4 + ((n >> 1) & 3)];
  A = make_a(apv, q, sc);
  const float f0 = p.ef[(g0 + (n >> 3)) * 16 + (n & 7) * 2];
  const float f1 = p.ef[(g0 + (n >> 3)) * 16 + (n & 7) * 2 + 1];
#pragma unroll
  for (int h = 0; h < 2; ++h) {
    const int fb = 32 * h + 8 * q;
    const float4 w00 = *(const float4*)(sc + CWPE + fb);
    const float4 w01 = *(const float4*)(sc + CWPE + fb + 4);
    const float4 w10 = *(const float4*)(sc + CWPE + 64 + fb);
    const float4 w11 = *(const float4*)(sc + CWPE + 64 + fb + 4);
    const float4 be0 = *(const float4*)(sc + CBPE + fb);
    const float4 be1 = *(const float4*)(sc + CBPE + fb + 4);
    uint4 pe;
    pe.x = pk2(fmaxf(fmaf(f0, w00.x, fmaf(f1, w10.x, be0.x)), 0.f),
               fmaxf(fmaf(f0, w00.y, fmaf(f1, w10.y, be0.y)), 0.f));
    pe.y = pk2(fmaxf(fmaf(f0, w00.z, fmaf(f1, w10.z, be0.z)), 0.f),
               fmaxf(fmaf(f0, w00.w, fmaf(f1, w10.w, be0.w)), 0.f));
    pe.z = pk2(fmaxf(fmaf(f0, w01.x, fmaf(f1, w11.x, be1.x)), 0.f),
               fmaxf(fmaf(f0, w01.y, fmaf(f1, w11.y, be1.y)), 0.f));
    pe.w = pk2(fmaxf(fmaf(f0, w01.z, fmaf(f1, w11.z, be1.z)), 0.f),
               fmaxf(fmaf(f0, w01.w, fmaf(f1, w11.w, be1.w)), 0.f));
    if (h == 0) e0 = __builtin_bit_cast(short8_t, pe);
    else        e1 = __builtin_bit_cast(short8_t, pe);
  }
}

// Build the 3 neighbor-tile h fragments for one chain (aP rows j-invariant).
__device__ __forceinline__ void build_h(short8_t* hf0, short8_t* hf1,
                                        const u16* aPb, const u16* BUF,
                                        int q, int n) {
  const int d = n >> 1;
  const int b_ln = d & 3;
  const uint4 av0 = *(const uint4*)(aPb + 0 * 256 + (d + 8 * q) * 8);
  const uint4 av1 = *(const uint4*)(aPb + 1 * 256 + (d + 8 * q) * 8);
#pragma unroll
  for (int j = 0; j < 3; ++j) {
    const int bp = (j >= b_ln) ? (j + 1) : j;   // j-th neighbor of b_ln
    const int re = (n & 8) + bp * 2 + (n & 1);
#pragma unroll
    for (int h = 0; h < 2; ++h) {
      const uint4 av = h ? av1 : av0;           // b61 already folded in
      const uint4 ev = *(const uint4*)(BUF + h * 512 + (re + 16 * q) * 8);
      uint4 ph;
      ph.x = pk2(fmaxf(blo(av.x) + blo(ev.x), 0.f),
                 fmaxf(bhi(av.x) + bhi(ev.x), 0.f));
      ph.y = pk2(fmaxf(blo(av.y) + blo(ev.y), 0.f),
                 fmaxf(bhi(av.y) + bhi(ev.y), 0.f));
      ph.z = pk2(fmaxf(blo(av.z) + blo(ev.z), 0.f),
                 fmaxf(bhi(av.z) + bhi(ev.z), 0.f));
      ph.w = pk2(fmaxf(blo(av.w) + blo(ev.w), 0.f),
                 fmaxf(bhi(av.w) + bhi(ev.w), 0.f));
      if (h == 0) hf0[j] = __builtin_bit_cast(short8_t, ph);
      else        hf1[j] = __builtin_bit_cast(short8_t, ph);
    }
  }
}

// Post linear + per-(g,b) L2 row normalization for one chain.
__device__ __forceinline__ void epilogue(const floatx4* acc3, const float* sc,
                                         float* out, int g0, int q, int n, bool ok) {
  float prr[4] = {0.f, 0.f, 0.f, 0.f}, pii[4] = {0.f, 0.f, 0.f, 0.f};
#pragma unroll
  for (int t = 0; t < 4; ++t) {
    const float wr = sc[CWPO + (16 * t + n) * 2];
    const float wi = sc[CWPO + (16 * t + n) * 2 + 1];
#pragma unroll
    for (int r = 0; r < 4; ++r) {
      const float e = fmaxf(acc3[t][r], 0.f);
      prr[r] = fmaf(e, wr, prr[r]);
      pii[r] = fmaf(e, wi, pii[r]);
    }
  }
  const float bpR = sc[CBPO], bpI = sc[CBPO + 1];
#pragma unroll
  for (int r = 0; r < 4; ++r) {
#pragma unroll
    for (int off = 1; off < 16; off <<= 1) {
      prr[r] += __shfl_xor(prr[r], off, 16);
      pii[r] += __shfl_xor(pii[r], off, 16);
    }
    prr[r] += bpR;
    pii[r] += bpI;
  }
  const int r = n >> 1, c = n & 1, rp = r ^ 1;
  const float pr_r  = sel4(r,  prr[0], prr[1], prr[2], prr[3]);
  const float pi_r  = sel4(r,  pii[0], pii[1], pii[2], pii[3]);
  const float pr_rp = sel4(rp, prr[0], prr[1], prr[2], prr[3]);
  const float pi_rp = sel4(rp, pii[0], pii[1], pii[2], pii[3]);
  const float num = c ? pi_r : pr_r;
  const float n2  = pr_r * pr_r + pi_r * pi_r + pr_rp * pr_rp + pi_rp * pi_rp;
  if (ok && n < 8) out[g0 * 16 + (4 * q + r) * 2 + c] = num / sqrtf(n2);
}

#define NBLK 256
#define NWAVE 8
#define PPW  2   // 256 blk * 8 waves * 2 chains * 2 = 8192 pairs = 16384 graphs

__global__ __launch_bounds__(512, 2)
__attribute__((amdgpu_waves_per_eu(2, 2)))
void hetgnn_mfma(Params p) {
  __shared__ __align__(16) u16   sW[WS_U16];            // 96 KB weights
  __shared__ __align__(16) u16   sAct[NWAVE * PW_U16];  // 48 KB: 8 x 2 x (BUF|aPb)
  __shared__ __align__(16) float sConst[CSZ];           // 4.25 KB

  const int tid  = threadIdx.x;
  const int wave = tid >> 6;
  const int l    = tid & 63;
  const int q    = l >> 4;
  const int n    = l & 15;

  // ---- stage + swizzle weights (f32 global -> bf16 B-frag LDS), 96 frags.
  //      Branchless W select (runtime-indexed ptr array would go to scratch).
  {
    for (int fi = wave; fi < 96; fi += NWAVE) {   // wave-uniform fi, 12/wave
      int t, h, mi;
      if (fi < 48) { mi = fi >> 4; const int loc = fi & 15; t = loc >> 2; h = loc & 3; }
      else { const int j = fi - 48; mi = 3 + (j >> 3); const int loc = j & 7; t = loc >> 1; h = loc & 1; }
      const float* W =
          (mi == 0) ? p.w51 : (mi == 1) ? p.w61 : (mi == 2) ? p.w71 :
          (mi == 3) ? p.w52 : (mi == 4) ? p.w53 : (mi == 5) ? p.w62 :
          (mi == 6) ? p.w63 : (mi == 7) ? p.w72 : p.w73;
      const int nn = 16 * t + n;
      const int k0 = 32 * h + q * 8;
      float w[8];
#pragma unroll
      for (int j = 0; j < 8; ++j) w[j] = W[(k0 + j) * 64 + nn];
      uint4 o;
      o.x = pk2(w[0], w[1]); o.y = pk2(w[2], w[3]);
      o.z = pk2(w[4], w[5]); o.w = pk2(w[6], w[7]);
      *(uint4*)(sW + fi * 512 + l * 8) = o;
    }
  }
  if (tid < 64) {
    sConst[CB51 + tid] = p.b51[tid];
    sConst[CB52 + tid] = p.b52[tid];
    sConst[CB53 + tid] = p.b53[tid];
    sConst[CB61 + tid] = p.b61[tid];
    sConst[CB62 + tid] = p.b62[tid];
    sConst[CB63 + tid] = p.b63[tid];
    sConst[CB71 + tid] = p.b71[tid];
    sConst[CB72 + tid] = p.b72[tid];
    sConst[CB73 + tid] = p.b73[tid];
    sConst[CWPA + tid] = p.wpa[tid];
    sConst[CBPA + tid] = p.bpa[tid];
    sConst[CBPE + tid] = p.bpe[tid];
  }
  if (tid < 128) {
    sConst[CWPO + tid] = p.wpost[tid];
    sConst[CWPE + tid] = p.wpe[tid];
  }
  if (tid < 2) sConst[CBPO + tid] = p.bpost[tid];
  __syncthreads();

  u16* BUF0 = sAct + wave * PW_U16;   // chain X: T1 = eP = Eb alias
  u16* aPb0 = BUF0 + 1024;
  u16* BUF1 = BUF0 + 1536;            // chain Y
  u16* aPb1 = BUF1 + 1024;

  const int wslot = blockIdx.x * NWAVE + wave;

#pragma unroll 1
  for (int pi = 0; pi < PPW; ++pi) {
    const int g0X = (wslot * 4 + 2 * pi) * 2;   // chain X: graphs g0X, g0X+1
    const int g0Y = g0X + 2;                    // chain Y: graphs g0Y, g0Y+1
    if (g0X + 2 > p.gtot) break;
    const bool okY = (g0Y + 2 <= p.gtot);
    const int gY  = okY ? g0Y : g0X;            // safe index for loads

    // ---------------- pre-layer, both chains ----------------
    frag2 AX, AY;
    short8_t ex0, ex1, ey0, ey1;
    prelayer(AX, ex0, ex1, p, sConst, g0X, q, n);
    prelayer(AY, ey0, ey1, p, sConst, gY,  q, n);

    // ---- aP = a @ w61[:64] (+ b61 pre-fold): iteration-invariant ----
    {
      floatx4 aaX[4], aaY[4];
      init_acc0(aaX); init_acc0(aaY);
      layerK64R2<4>(aaX, aaY, AX.f0, AX.f1, AY.f0, AY.f1, sW + OFF_W61, l);
      scatter_aP(aPb0, aaX, q, n, sConst + CB61);
      scatter_aP(aPb1, aaY, q, n, sConst + CB61);
    }

    // ---------------- 2 shared-weight update iterations ----------------
#pragma unroll 1
    for (int it = 0; it < 2; ++it) {
      if (it == 1) {
        ex0 = ldA(BUF0, l); ex1 = ldA(BUF0 + 512, l);   // new e from it0
        ey0 = ldA(BUF1, l); ey1 = ldA(BUF1 + 512, l);
      }

      // ---- mlp5 -> m1 (packed raw bf16; relu deferred to agg max) ----
      u32 m1pX[8], m1pY[8];
      {
        floatx4 aX[4], aY[4];
        init_accL(aX, sConst + CB51, n); init_accL(aY, sConst + CB51, n);
        const short8_t fx[4] = {AX.f0, AX.f1, ex0, ex1};
        const short8_t fy[4] = {AY.f0, AY.f1, ey0, ey1};
        layerK128R2(aX, aY, fx, fy, sW + OFF_W51, l);
        scatter_relu_bf16(BUF0, aX, q, n);
        scatter_relu_bf16(BUF1, aY, q, n);
        floatx4 bX[4], bY[4];
        init_accL(bX, sConst + CB52, n); init_accL(bY, sConst + CB52, n);
        {
          const short8_t gx0 = ldA(BUF0, l), gx1 = ldA(BUF0 + 512, l);
          const short8_t gy0 = ldA(BUF1, l), gy1 = ldA(BUF1 + 512, l);
          layerK64R2<2>(bX, bY, gx0, gx1, gy0, gy1, sW + OFF_W52, l);
        }
        scatter_relu_bf16(BUF0, bX, q, n);
        scatter_relu_bf16(BUF1, bY, q, n);
        floatx4 cX[4], cY[4];
        init_accL(cX, sConst + CB53, n); init_accL(cY, sConst + CB53, n);
        {
          const short8_t gx0 = ldA(BUF0, l), gx1 = ldA(BUF0 + 512, l);
          const short8_t gy0 = ldA(BUF1, l), gy1 = ldA(BUF1 + 512, l);
          layerK64R2<2>(cX, cY, gx0, gx1, gy0, gy1, sW + OFF_W53, l);
        }
#pragma unroll
        for (int t = 0; t < 4; ++t) {
          m1pX[2 * t + 0] = pk2(cX[t][0], cX[t][1]);
          m1pX[2 * t + 1] = pk2(cX[t][2], cX[t][3]);
          m1pY[2 * t + 0] = pk2(cY[t][0], cY[t][1]);
          m1pY[2 * t + 1] = pk2(cY[t][2], cY[t][3]);
        }
      }

      // ---- mlp6 -> m2: 3 neighbor-tiles; h-frags hoisted so eP (=BUF)
      //      dies before the first T1 (=BUF) scatter of the j-loop ----
      u32 m2pX[8], m2pY[8];
      {
        floatx4 eX[4], eY[4];
        init_acc0(eX); init_acc0(eY);
        layerK64R2<4>(eX, eY, ex0, ex1, ey0, ey1, sW + OFF_W61 + 2 * 512, l);
        scatter_bf16(BUF0, eX, q, n);   // eP
        scatter_bf16(BUF1, eY, q, n);

        short8_t hfX0[3], hfX1[3], hfY0[3], hfY1[3];
        build_h(hfX0, hfX1, aPb0, BUF0, q, n);
        build_h(hfY0, hfY1, aPb1, BUF1, q, n);

#pragma unroll
        for (int j = 0; j < 3; ++j) {
          floatx4 uX[4], uY[4];
          init_accL(uX, sConst + CB62, n); init_accL(uY, sConst + CB62, n);
          layerK64R2<2>(uX, uY, hfX0[j], hfX1[j], hfY0[j], hfY1[j], sW + OFF_W62, l);
          scatter_relu_bf16(BUF0, uX, q, n);
          scatter_relu_bf16(BUF1, uY, q, n);
          floatx4 vX[4], vY[4];
          init_accL(vX, sConst + CB63, n); init_accL(vY, sConst + CB63, n);
          {
            const short8_t gx0 = ldA(BUF0, l), gx1 = ldA(BUF0 + 512, l);
            const short8_t gy0 = ldA(BUF1, l), gy1 = ldA(BUF1 + 512, l);
            layerK64R2<2>(vX, vY, gx0, gx1, gy0, gy1, sW + OFF_W63, l);
          }
#pragma unroll
          for (int t = 0; t < 4; ++t) {
#pragma unroll
            for (int h = 0; h < 2; ++h) {
              const u32 cX = pk2(vX[t][2 * h], vX[t][2 * h + 1]);
              const u32 cY = pk2(vY[t][2 * h], vY[t][2 * h + 1]);
              m2pX[2 * t + h] = (j == 0) ? cX : pkmax(m2pX[2 * t + h], cX);
              m2pY[2 * t + h] = (j == 0) ? cY : pkmax(m2pY[2 * t + h], cY);
            }
          }
        }
      }

      // ---- agg = relu(max(m1[r^1], m2)) via pkmax-with-0, + mlp7 ----
      {
        u32 agX[8], agY[8];
#pragma unroll
        for (int i = 0; i < 8; ++i) {
          agX[i] = pkmax(pkmax(ror16(m1pX[i]), m2pX[i]), 0u);
          agY[i] = pkmax(pkmax(ror16(m1pY[i]), m2pY[i]), 0u);
        }
        scatter_pk(BUF0, agX, q, n);
        scatter_pk(BUF1, agY, q, n);
        floatx4 aX[4], aY[4];
        init_accL(aX, sConst + CB71, n); init_accL(aY, sConst + CB71, n);
        {
          const short8_t gx0 = ldA(BUF0, l), gx1 = ldA(BUF0 + 512, l);
          const short8_t gy0 = ldA(BUF1, l), gy1 = ldA(BUF1 + 512, l);
          const short8_t fx[4] = {gx0, gx1, ex0, ex1};
          const short8_t fy[4] = {gy0, gy1, ey0, ey1};
          layerK128R2(aX, aY, fx, fy, sW + OFF_W71, l);
        }
        scatter_relu_bf16(BUF0, aX, q, n);
        scatter_relu_bf16(BUF1, aY, q, n);
        floatx4 bX[4], bY[4];
        init_accL(bX, sConst + CB72, n); init_accL(bY, sConst + CB72, n);
        {
          const short8_t gx0 = ldA(BUF0, l), gx1 = ldA(BUF0 + 512, l);
          const short8_t gy0 = ldA(BUF1, l), gy1 = ldA(BUF1 + 512, l);
          layerK64R2<2>(bX, bY, gx0, gx1, gy0, gy1, sW + OFF_W72, l);
        }
        scatter_relu_bf16(BUF0, bX, q, n);
        scatter_relu_bf16(BUF1, bY, q, n);
        floatx4 cX[4], cY[4];
        init_accL(cX, sConst + CB73, n); init_accL(cY, sConst + CB73, n);
        {
          const short8_t gx0 = ldA(BUF0, l), gx1 = ldA(BUF0 + 512, l);
          const short8_t gy0 = ldA(BUF1, l), gy1 = ldA(BUF1 + 512, l);
          layerK64R2<2>(cX, cY, gx0, gx1, gy0, gy1, sW + OFF_W73, l);
        }

        if (it == 0) {
          scatter_relu_bf16(BUF0, cX, q, n);   // new e (cross-lane -> LDS)
          scatter_relu_bf16(BUF1, cY, q, n);
        } else {
          epilogue(cX, sConst, p.out, g0X, q, n, true);
          epilogue(cY, sConst, p.out, g0Y, q, n, okY);
        }
      }
    }
  }
}

extern "C" void kernel_launch(void* const* d_in, const int* in_sizes, int n_in,
                              void* d_out, int out_size, void* d_ws, size_t ws_size,
                              hipStream_t stream) {
  Params p;
  p.ap    = (const float*)d_in[0];
  p.ef    = (const float*)d_in[1];
  p.wpa   = (const float*)d_in[2];  p.bpa   = (const float*)d_in[3];
  p.wpe   = (const float*)d_in[4];  p.bpe   = (const float*)d_in[5];
  p.w51   = (const float*)d_in[6];  p.b51   = (const float*)d_in[7];
  p.w52   = (const float*)d_in[8];  p.b52   = (const float*)d_in[9];
  p.w53   = (const float*)d_in[10]; p.b53   = (const float*)d_in[11];
  p.w61   = (const float*)d_in[12]; p.b61   = (const float*)d_in[13];
  p.w62   = (const float*)d_in[14]; p.b62   = (const float*)d_in[15];
  p.w63   = (const float*)d_in[16]; p.b63   = (const float*)d_in[17];
  p.w71   = (const float*)d_in[18]; p.b71   = (const float*)d_in[19];
  p.w72   = (const float*)d_in[20]; p.b72   = (const float*)d_in[21];
  p.w73   = (const float*)d_in[22]; p.b73   = (const float*)d_in[23];
  p.wpost = (const float*)d_in[24]; p.bpost = (const float*)d_in[25];
  p.out   = (float*)d_out;
  p.gtot  = in_sizes[0] / 4;  // G from ap_feat [G,B,1]

  hipLaunchKernelGGL(hetgnn_mfma, dim3(NBLK), dim3(512), 0, stream, p);
}